// Round 1
// baseline (1020.389 us; speedup 1.0000x reference)
//
#include <hip/hip_runtime.h>
#include <hip/hip_bf16.h>
#include <stdint.h>

#define N_TOK 8192
#define DIN   1024
#define DHID  4096
#define DOUT  1024
#define NE    8

typedef __attribute__((ext_vector_type(8))) __bf16 bf16x8;
typedef __attribute__((ext_vector_type(4))) float  f32x4;

// RNE float->bf16 (finite inputs)
__device__ __forceinline__ unsigned short f2bfu(float f) {
    union { float f; unsigned u; } a; a.f = f;
    unsigned r = a.u + 0x7FFF + ((a.u >> 16) & 1);
    return (unsigned short)(r >> 16);
}

__device__ __forceinline__ void gload_lds16(const void* g, void* l) {
    __builtin_amdgcn_global_load_lds(
        (__attribute__((address_space(1))) void*)(void*)g,
        (__attribute__((address_space(3))) void*)l,
        16, 0, 0);
}

// ---------------- cast x -> bf16 ----------------
__global__ void cast_x_kernel(const float* __restrict__ in, unsigned short* __restrict__ out) {
    int i = blockIdx.x * blockDim.x + threadIdx.x;   // one float4 per thread, exact grid
    float4 v = ((const float4*)in)[i];
    ushort4 o;
    o.x = f2bfu(v.x); o.y = f2bfu(v.y); o.z = f2bfu(v.z); o.w = f2bfu(v.w);
    ((ushort4*)out)[i] = o;
}

// ------------- cast + transpose weights: in [R][C] f32 -> out [C][R] bf16, per expert -------------
__global__ void transpose_cast_kernel(const float* __restrict__ in, unsigned short* __restrict__ out,
                                      int R, int C) {
    __shared__ float t[32][33];
    const float* ine = in + (size_t)blockIdx.z * R * C;
    unsigned short* oute = out + (size_t)blockIdx.z * R * C;
    int c0 = blockIdx.x * 32, r0 = blockIdx.y * 32;
    int tx = threadIdx.x, ty = threadIdx.y;          // (32,8)
    #pragma unroll
    for (int j = 0; j < 32; j += 8)
        t[ty + j][tx] = ine[(size_t)(r0 + ty + j) * C + c0 + tx];
    __syncthreads();
    #pragma unroll
    for (int j = 0; j < 32; j += 8)
        oute[(size_t)(c0 + ty + j) * R + r0 + tx] = f2bfu(t[tx][ty + j]);
}

// ---------------- gating: scores, softmax, top-2, expert lists ----------------
__global__ void gate_kernel(const float* __restrict__ x, const float* __restrict__ Wg,
                            const float* __restrict__ bg, int* __restrict__ counts,
                            int* __restrict__ tok_list, int* __restrict__ slot_list,
                            float* __restrict__ wslot) {
    int wv = threadIdx.x >> 6, lane = threadIdx.x & 63;
    int n = blockIdx.x * 4 + wv;
    float acc[NE];
    #pragma unroll
    for (int e = 0; e < NE; e++) acc[e] = 0.f;
    const float* xr = x + (size_t)n * DIN;
    #pragma unroll 4
    for (int i = 0; i < DIN / 64; i++) {
        int d = i * 64 + lane;
        float xv = xr[d];
        const float4* wr = (const float4*)(Wg + (size_t)d * NE);
        float4 w0 = wr[0], w1 = wr[1];
        acc[0] += xv * w0.x; acc[1] += xv * w0.y; acc[2] += xv * w0.z; acc[3] += xv * w0.w;
        acc[4] += xv * w1.x; acc[5] += xv * w1.y; acc[6] += xv * w1.z; acc[7] += xv * w1.w;
    }
    #pragma unroll
    for (int off = 32; off; off >>= 1)
        #pragma unroll
        for (int e = 0; e < NE; e++) acc[e] += __shfl_down(acc[e], off);
    if (lane == 0) {
        float s[NE], p[NE];
        float mx = -1e30f;
        #pragma unroll
        for (int e = 0; e < NE; e++) { s[e] = acc[e] + bg[e]; mx = fmaxf(mx, s[e]); }
        float sum = 0.f;
        #pragma unroll
        for (int e = 0; e < NE; e++) { p[e] = expf(s[e] - mx); sum += p[e]; }
        float inv = 1.f / sum;
        int e0 = 0;
        #pragma unroll
        for (int e = 1; e < NE; e++) if (s[e] > s[e0]) e0 = e;
        int e1 = (e0 == 0) ? 1 : 0;
        #pragma unroll
        for (int e = 0; e < NE; e++) if (e != e0 && s[e] > s[e1]) e1 = e;
        float p0 = p[e0] * inv, p1 = p[e1] * inv;
        float rn = 1.f / (p0 + p1 + 1e-8f);
        int pos0 = atomicAdd(&counts[e0], 1);
        tok_list[e0 * N_TOK + pos0] = n; slot_list[e0 * N_TOK + pos0] = 2 * n;     wslot[e0 * N_TOK + pos0] = p0 * rn;
        int pos1 = atomicAdd(&counts[e1], 1);
        tok_list[e1 * N_TOK + pos1] = n; slot_list[e1 * N_TOK + pos1] = 2 * n + 1; wslot[e1 * N_TOK + pos1] = p1 * rn;
    }
}

// ---------------- grouped gather-GEMM, 128x128 tile, BK=64, bf16 MFMA ----------------
// A: gathered rows of Asrc (stride KDIM). Bt: [NE][NDIM][KDIM] bf16 (transposed weights).
// IS_GEMM1: epilogue = relu(acc + bias) -> bf16 h[slot].  else: atomicAdd(out[token], w*(acc+bias)).
template <int KDIM, int NDIM, bool IS_GEMM1>
__global__ __launch_bounds__(256, 2)
void moe_gemm(const unsigned short* __restrict__ Asrc, const unsigned short* __restrict__ Bt,
              const float* __restrict__ bias, unsigned short* __restrict__ Hdst,
              float* __restrict__ Odst, const int* __restrict__ counts,
              const int* __restrict__ tok_list, const int* __restrict__ slot_list,
              const float* __restrict__ wslot) {
    int e = blockIdx.z;
    int tile_m = blockIdx.y;
    int tile_n = blockIdx.x;
    int count = counts[e];
    if (tile_m * 128 >= count) return;

    __shared__ __align__(16) unsigned short As[128 * 64];
    __shared__ __align__(16) unsigned short Bs[128 * 64];
    __shared__ int rowid_s[128];   // A-gather row id (token for gemm1, slot for gemm2)
    __shared__ int outid_s[128];   // output row id (slot for gemm1, token for gemm2)
    __shared__ float w_s[128];

    int tid = threadIdx.x;
    if (tid < 128) {
        int r = tile_m * 128 + tid;
        int rr = (r < count) ? r : tile_m * 128;  // clamp padding rows to a valid row
        int base = e * N_TOK + rr;
        if (IS_GEMM1) { rowid_s[tid] = tok_list[base]; outid_s[tid] = slot_list[base]; }
        else          { rowid_s[tid] = slot_list[base]; outid_s[tid] = tok_list[base]; w_s[tid] = wslot[base]; }
    }
    __syncthreads();

    int lane = tid & 63;
    int wv = tid >> 6;

    // staging: 32 chunks of 1KB (8 rows x 64 bf16); wave wv owns chunks wv*4..wv*4+3 of A and of B
    const unsigned short* aptr[4];
    const unsigned short* bptr[4];
    #pragma unroll
    for (int i = 0; i < 4; i++) {
        int c = wv * 4 + i;
        int row = c * 8 + (lane >> 3);
        aptr[i] = Asrc + (size_t)rowid_s[row] * KDIM + (lane & 7) * 8;
        bptr[i] = Bt + ((size_t)e * NDIM + tile_n * 128 + row) * KDIM + (lane & 7) * 8;
    }

    f32x4 acc[4][4];
    #pragma unroll
    for (int i = 0; i < 4; i++)
        #pragma unroll
        for (int j = 0; j < 4; j++) acc[i][j] = (f32x4){0.f, 0.f, 0.f, 0.f};

    int wm = (wv >> 1) * 64, wn = (wv & 1) * 64;
    int r16 = lane & 15, quad = lane >> 4;

    for (int kk = 0; kk < KDIM / 64; kk++) {
        #pragma unroll
        for (int i = 0; i < 4; i++) {
            gload_lds16(aptr[i] + kk * 64, (void*)(As + (wv * 4 + i) * 512));
            gload_lds16(bptr[i] + kk * 64, (void*)(Bs + (wv * 4 + i) * 512));
        }
        __syncthreads();
        #pragma unroll
        for (int kh = 0; kh < 2; kh++) {
            bf16x8 av[4], bv[4];
            #pragma unroll
            for (int i = 0; i < 4; i++)
                av[i] = *(const bf16x8*)(As + (wm + i * 16 + r16) * 64 + kh * 32 + quad * 8);
            #pragma unroll
            for (int j = 0; j < 4; j++)
                bv[j] = *(const bf16x8*)(Bs + (wn + j * 16 + r16) * 64 + kh * 32 + quad * 8);
            #pragma unroll
            for (int i = 0; i < 4; i++)
                #pragma unroll
                for (int j = 0; j < 4; j++)
                    acc[i][j] = __builtin_amdgcn_mfma_f32_16x16x32_bf16(av[i], bv[j], acc[i][j], 0, 0, 0);
        }
        __syncthreads();
    }

    // epilogue: D row = quad*4+reg, col = lane&15 within each 16x16 tile
    #pragma unroll
    for (int i = 0; i < 4; i++) {
        #pragma unroll
        for (int reg = 0; reg < 4; reg++) {
            int r = wm + i * 16 + quad * 4 + reg;
            if (tile_m * 128 + r >= count) continue;
            #pragma unroll
            for (int j = 0; j < 4; j++) {
                int col = tile_n * 128 + wn + j * 16 + r16;
                float v = acc[i][j][reg] + bias[(size_t)e * NDIM + col];
                if (IS_GEMM1) {
                    v = fmaxf(v, 0.f);
                    Hdst[(size_t)outid_s[r] * NDIM + col] = f2bfu(v);
                } else {
                    atomicAdd(&Odst[(size_t)outid_s[r] * NDIM + col], w_s[r] * v);
                }
            }
        }
    }
}

extern "C" void kernel_launch(void* const* d_in, const int* in_sizes, int n_in,
                              void* d_out, int out_size, void* d_ws, size_t ws_size,
                              hipStream_t stream) {
    const float* x  = (const float*)d_in[0];
    const float* W1 = (const float*)d_in[1];
    const float* b1 = (const float*)d_in[2];
    const float* W2 = (const float*)d_in[3];
    const float* b2 = (const float*)d_in[4];
    const float* Wg = (const float*)d_in[5];
    const float* bg = (const float*)d_in[6];
    float* out = (float*)d_out;

    char* ws = (char*)d_ws;
    // workspace layout (bytes)
    unsigned short* xb  = (unsigned short*)(ws + 0);            // 16 MB
    unsigned short* w1t = (unsigned short*)(ws + 16777216);     // 64 MB  [E][DHID][DIN]
    unsigned short* w2t = (unsigned short*)(ws + 83886080);     // 64 MB  [E][DOUT][DHID]
    unsigned short* h   = (unsigned short*)(ws + 150994944);    // 128 MB [2N][DHID]
    int*   counts    = (int*)(ws + 285212672);
    int*   tok_list  = (int*)(ws + 285212928);
    int*   slot_list = (int*)(ws + 285475072);
    float* wslot     = (float*)(ws + 285737216);

    hipMemsetAsync(counts, 0, 256, stream);
    hipMemsetAsync(d_out, 0, (size_t)out_size * sizeof(float), stream);

    cast_x_kernel<<<(N_TOK * DIN / 4) / 256, 256, 0, stream>>>(x, xb);
    transpose_cast_kernel<<<dim3(DHID / 32, DIN / 32, NE), dim3(32, 8), 0, stream>>>(W1, w1t, DIN, DHID);
    transpose_cast_kernel<<<dim3(DOUT / 32, DHID / 32, NE), dim3(32, 8), 0, stream>>>(W2, w2t, DHID, DOUT);
    gate_kernel<<<N_TOK / 4, 256, 0, stream>>>(x, Wg, bg, counts, tok_list, slot_list, wslot);

    moe_gemm<DIN, DHID, true><<<dim3(DHID / 128, N_TOK / 128, NE), 256, 0, stream>>>(
        xb, w1t, b1, h, nullptr, counts, tok_list, slot_list, wslot);
    moe_gemm<DHID, DOUT, false><<<dim3(DOUT / 128, N_TOK / 128, NE), 256, 0, stream>>>(
        h, w2t, b2, nullptr, out, counts, tok_list, slot_list, wslot);
}

// Round 2
// 953.085 us; speedup vs baseline: 1.0706x; 1.0706x over previous
//
#include <hip/hip_runtime.h>
#include <hip/hip_bf16.h>
#include <stdint.h>

#define N_TOK 8192
#define DIN   1024
#define DHID  4096
#define DOUT  1024
#define NE    8

typedef __attribute__((ext_vector_type(8))) __bf16 bf16x8;
typedef __attribute__((ext_vector_type(4))) float  f32x4;
typedef __attribute__((ext_vector_type(8))) unsigned short u16x8;

// RNE float->bf16 (finite inputs)
__device__ __forceinline__ unsigned short f2bfu(float f) {
    union { float f; unsigned u; } a; a.f = f;
    unsigned r = a.u + 0x7FFF + ((a.u >> 16) & 1);
    return (unsigned short)(r >> 16);
}

__device__ __forceinline__ void gload_lds16(const void* g, void* l) {
    __builtin_amdgcn_global_load_lds(
        (__attribute__((address_space(1))) void*)(void*)g,
        (__attribute__((address_space(3))) void*)l,
        16, 0, 0);
}

// ------------- cast + transpose weights: in [R][C] f32 -> out [C][R] bf16, per expert -------------
// 64x64 tile; reads float4-coalesced, writes ushort8 (16B) fully vectorized.
__global__ void transpose_cast_kernel(const float* __restrict__ in, unsigned short* __restrict__ out,
                                      int R, int C) {
    __shared__ float t[64][65];
    const size_t RC = (size_t)R * C;
    const float* ine = in + (size_t)blockIdx.z * RC;
    unsigned short* oute = out + (size_t)blockIdx.z * RC;
    int c0 = blockIdx.x * 64, r0 = blockIdx.y * 64;
    int tid = threadIdx.x;
    #pragma unroll
    for (int it = 0; it < 4; it++) {
        int idx = it * 256 + tid;
        int r = idx >> 4, cq = (idx & 15) * 4;
        float4 v = *(const float4*)(ine + (size_t)(r0 + r) * C + c0 + cq);
        t[r][cq] = v.x; t[r][cq + 1] = v.y; t[r][cq + 2] = v.z; t[r][cq + 3] = v.w;
    }
    __syncthreads();
    #pragma unroll
    for (int it = 0; it < 2; it++) {
        int u = it * 256 + tid;
        int c = u >> 3, g = (u & 7) * 8;
        u16x8 o;
        #pragma unroll
        for (int v = 0; v < 8; v++) o[v] = f2bfu(t[g + v][c]);
        *(u16x8*)(oute + (size_t)(c0 + c) * R + r0 + g) = o;
    }
}

// ---------------- gating: scores, softmax, top-2, expert lists; also emits xb (x cast to bf16) ----------------
__global__ void gate_kernel(const float* __restrict__ x, const float* __restrict__ Wg,
                            const float* __restrict__ bg, int* __restrict__ counts,
                            int* __restrict__ tok_list, int* __restrict__ slot_list,
                            float* __restrict__ wslot, unsigned short* __restrict__ xb) {
    int wv = threadIdx.x >> 6, lane = threadIdx.x & 63;
    int n = blockIdx.x * 4 + wv;
    float acc[NE];
    #pragma unroll
    for (int e = 0; e < NE; e++) acc[e] = 0.f;
    const float* xr = x + (size_t)n * DIN;
    unsigned short* xbr = xb + (size_t)n * DIN;
    #pragma unroll
    for (int i = 0; i < DIN / 256; i++) {
        int d = i * 256 + lane * 4;
        float4 xv = *(const float4*)(xr + d);
        ushort4 o;
        o.x = f2bfu(xv.x); o.y = f2bfu(xv.y); o.z = f2bfu(xv.z); o.w = f2bfu(xv.w);
        *(ushort4*)(xbr + d) = o;
        const float* w = Wg + (size_t)d * NE;
        #pragma unroll
        for (int u = 0; u < 4; u++) {
            float xs = (&xv.x)[u];
            float4 w0 = *(const float4*)(w + u * NE);
            float4 w1 = *(const float4*)(w + u * NE + 4);
            acc[0] += xs * w0.x; acc[1] += xs * w0.y; acc[2] += xs * w0.z; acc[3] += xs * w0.w;
            acc[4] += xs * w1.x; acc[5] += xs * w1.y; acc[6] += xs * w1.z; acc[7] += xs * w1.w;
        }
    }
    #pragma unroll
    for (int off = 32; off; off >>= 1)
        #pragma unroll
        for (int e = 0; e < NE; e++) acc[e] += __shfl_down(acc[e], off);
    if (lane == 0) {
        float s[NE], p[NE];
        float mx = -1e30f;
        #pragma unroll
        for (int e = 0; e < NE; e++) { s[e] = acc[e] + bg[e]; mx = fmaxf(mx, s[e]); }
        float sum = 0.f;
        #pragma unroll
        for (int e = 0; e < NE; e++) { p[e] = expf(s[e] - mx); sum += p[e]; }
        float inv = 1.f / sum;
        int e0 = 0;
        #pragma unroll
        for (int e = 1; e < NE; e++) if (s[e] > s[e0]) e0 = e;
        int e1 = (e0 == 0) ? 1 : 0;
        #pragma unroll
        for (int e = 0; e < NE; e++) if (e != e0 && s[e] > s[e1]) e1 = e;
        float p0 = p[e0] * inv, p1 = p[e1] * inv;
        float rn = 1.f / (p0 + p1 + 1e-8f);
        int pos0 = atomicAdd(&counts[e0], 1);
        tok_list[e0 * N_TOK + pos0] = n; slot_list[e0 * N_TOK + pos0] = 2 * n;     wslot[e0 * N_TOK + pos0] = p0 * rn;
        int pos1 = atomicAdd(&counts[e1], 1);
        tok_list[e1 * N_TOK + pos1] = n; slot_list[e1 * N_TOK + pos1] = 2 * n + 1; wslot[e1 * N_TOK + pos1] = p1 * rn;
    }
}

// ---------------- grouped gather-GEMM, 128x128 tile, BK=64, bf16 MFMA ----------------
// LDS staging uses an XOR swizzle: within each 8-row x 64-col (1KB) chunk, the 16B k-group
// k8 of row r is stored at position (k8 ^ (r&7)). Legal with global_load_lds because each
// lane supplies its own global address; kills the 128B-row-stride bank aliasing.
template <int KDIM, int NDIM, bool IS_GEMM1>
__global__ __launch_bounds__(256, 4)
void moe_gemm(const unsigned short* __restrict__ Asrc, const unsigned short* __restrict__ Bt,
              const float* __restrict__ bias, unsigned short* __restrict__ Hdst,
              float* __restrict__ Odst, const int* __restrict__ counts,
              const int* __restrict__ tok_list, const int* __restrict__ slot_list,
              const float* __restrict__ wslot) {
    int e = blockIdx.z;
    int tile_m = blockIdx.y;
    int tile_n = blockIdx.x;
    int count = counts[e];
    if (tile_m * 128 >= count) return;

    __shared__ __align__(16) unsigned short As[128 * 64];
    __shared__ __align__(16) unsigned short Bs[128 * 64];
    __shared__ int rowid_s[128];
    __shared__ int outid_s[128];
    __shared__ float w_s[128];

    int tid = threadIdx.x;
    if (tid < 128) {
        int r = tile_m * 128 + tid;
        int rr = (r < count) ? r : tile_m * 128;
        int base = e * N_TOK + rr;
        if (IS_GEMM1) { rowid_s[tid] = tok_list[base]; outid_s[tid] = slot_list[base]; }
        else          { rowid_s[tid] = slot_list[base]; outid_s[tid] = tok_list[base]; w_s[tid] = wslot[base]; }
    }
    __syncthreads();

    int lane = tid & 63;
    int wv = tid >> 6;

    // staging: 16 A-chunks + 16 B-chunks of 1KB (8 rows x 64 bf16); wave wv owns 4 of each.
    // lane -> (row_in_chunk = lane>>3, swizzled k-group = (lane&7) ^ (lane>>3))
    int ric = lane >> 3;
    int k8  = (lane & 7) ^ ric;
    const unsigned short* aptr[4];
    const unsigned short* bptr[4];
    #pragma unroll
    for (int i = 0; i < 4; i++) {
        int c = wv * 4 + i;
        int row = c * 8 + ric;
        aptr[i] = Asrc + (size_t)rowid_s[row] * KDIM + k8 * 8;
        bptr[i] = Bt + ((size_t)e * NDIM + tile_n * 128 + row) * KDIM + k8 * 8;
    }

    f32x4 acc[4][4];
    #pragma unroll
    for (int i = 0; i < 4; i++)
        #pragma unroll
        for (int j = 0; j < 4; j++) acc[i][j] = (f32x4){0.f, 0.f, 0.f, 0.f};

    int wm = (wv >> 1) * 64, wn = (wv & 1) * 64;
    int r16 = lane & 15, quad = lane >> 4;

    for (int kk = 0; kk < KDIM / 64; kk++) {
        #pragma unroll
        for (int i = 0; i < 4; i++) {
            gload_lds16(aptr[i] + kk * 64, (void*)(As + (wv * 4 + i) * 512));
            gload_lds16(bptr[i] + kk * 64, (void*)(Bs + (wv * 4 + i) * 512));
        }
        __syncthreads();
        #pragma unroll
        for (int kh = 0; kh < 2; kh++) {
            int swk = ((kh * 4 + quad) ^ (r16 & 7)) * 8;   // un-swizzle at read time
            bf16x8 av[4], bv[4];
            #pragma unroll
            for (int i = 0; i < 4; i++)
                av[i] = *(const bf16x8*)(As + (wm + i * 16 + r16) * 64 + swk);
            #pragma unroll
            for (int j = 0; j < 4; j++)
                bv[j] = *(const bf16x8*)(Bs + (wn + j * 16 + r16) * 64 + swk);
            #pragma unroll
            for (int i = 0; i < 4; i++)
                #pragma unroll
                for (int j = 0; j < 4; j++)
                    acc[i][j] = __builtin_amdgcn_mfma_f32_16x16x32_bf16(av[i], bv[j], acc[i][j], 0, 0, 0);
        }
        __syncthreads();
    }

    // epilogue: D row = quad*4+reg, col = lane&15 within each 16x16 tile
    #pragma unroll
    for (int i = 0; i < 4; i++) {
        #pragma unroll
        for (int reg = 0; reg < 4; reg++) {
            int r = wm + i * 16 + quad * 4 + reg;
            if (tile_m * 128 + r >= count) continue;
            #pragma unroll
            for (int j = 0; j < 4; j++) {
                int col = tile_n * 128 + wn + j * 16 + r16;
                float v = acc[i][j][reg] + bias[(size_t)e * NDIM + col];
                if (IS_GEMM1) {
                    v = fmaxf(v, 0.f);
                    Hdst[(size_t)outid_s[r] * NDIM + col] = f2bfu(v);
                } else {
                    atomicAdd(&Odst[(size_t)outid_s[r] * NDIM + col], w_s[r] * v);
                }
            }
        }
    }
}

extern "C" void kernel_launch(void* const* d_in, const int* in_sizes, int n_in,
                              void* d_out, int out_size, void* d_ws, size_t ws_size,
                              hipStream_t stream) {
    const float* x  = (const float*)d_in[0];
    const float* W1 = (const float*)d_in[1];
    const float* b1 = (const float*)d_in[2];
    const float* W2 = (const float*)d_in[3];
    const float* b2 = (const float*)d_in[4];
    const float* Wg = (const float*)d_in[5];
    const float* bg = (const float*)d_in[6];
    float* out = (float*)d_out;

    char* ws = (char*)d_ws;
    unsigned short* xb  = (unsigned short*)(ws + 0);            // 16 MB
    unsigned short* w1t = (unsigned short*)(ws + 16777216);     // 64 MB  [E][DHID][DIN]
    unsigned short* w2t = (unsigned short*)(ws + 83886080);     // 64 MB  [E][DOUT][DHID]
    unsigned short* h   = (unsigned short*)(ws + 150994944);    // 128 MB [2N][DHID]
    int*   counts    = (int*)(ws + 285212672);
    int*   tok_list  = (int*)(ws + 285212928);
    int*   slot_list = (int*)(ws + 285475072);
    float* wslot     = (float*)(ws + 285737216);

    hipMemsetAsync(counts, 0, 256, stream);
    hipMemsetAsync(d_out, 0, (size_t)out_size * sizeof(float), stream);

    transpose_cast_kernel<<<dim3(DHID / 64, DIN / 64, NE), 256, 0, stream>>>(W1, w1t, DIN, DHID);
    transpose_cast_kernel<<<dim3(DOUT / 64, DHID / 64, NE), 256, 0, stream>>>(W2, w2t, DHID, DOUT);
    gate_kernel<<<N_TOK / 4, 256, 0, stream>>>(x, Wg, bg, counts, tok_list, slot_list, wslot, xb);

    moe_gemm<DIN, DHID, true><<<dim3(DHID / 128, N_TOK / 128, NE), 256, 0, stream>>>(
        xb, w1t, b1, h, nullptr, counts, tok_list, slot_list, wslot);
    moe_gemm<DHID, DOUT, false><<<dim3(DOUT / 128, N_TOK / 128, NE), 256, 0, stream>>>(
        h, w2t, b2, nullptr, out, counts, tok_list, slot_list, wslot);
}

// Round 3
// 896.208 us; speedup vs baseline: 1.1386x; 1.0635x over previous
//
#include <hip/hip_runtime.h>
#include <hip/hip_bf16.h>
#include <stdint.h>

#define N_TOK 8192
#define DIN   1024
#define DHID  4096
#define DOUT  1024
#define NE    8

typedef __attribute__((ext_vector_type(8))) __bf16 bf16x8;
typedef __attribute__((ext_vector_type(4))) float  f32x4;
typedef __attribute__((ext_vector_type(8))) unsigned short u16x8;

// RNE float->bf16 (finite inputs)
__device__ __forceinline__ unsigned short f2bfu(float f) {
    union { float f; unsigned u; } a; a.f = f;
    unsigned r = a.u + 0x7FFF + ((a.u >> 16) & 1);
    return (unsigned short)(r >> 16);
}

__device__ __forceinline__ void gload_lds16(const void* g, void* l) {
    __builtin_amdgcn_global_load_lds(
        (__attribute__((address_space(1))) void*)(void*)g,
        (__attribute__((address_space(3))) void*)l,
        16, 0, 0);
}

// ------------- cast + transpose weights: in [R][C] f32 -> out [C][R] bf16, per expert -------------
__global__ void transpose_cast_kernel(const float* __restrict__ in, unsigned short* __restrict__ out,
                                      int R, int C) {
    __shared__ float t[64][65];
    const size_t RC = (size_t)R * C;
    const float* ine = in + (size_t)blockIdx.z * RC;
    unsigned short* oute = out + (size_t)blockIdx.z * RC;
    int c0 = blockIdx.x * 64, r0 = blockIdx.y * 64;
    int tid = threadIdx.x;
    #pragma unroll
    for (int it = 0; it < 4; it++) {
        int idx = it * 256 + tid;
        int r = idx >> 4, cq = (idx & 15) * 4;
        float4 v = *(const float4*)(ine + (size_t)(r0 + r) * C + c0 + cq);
        t[r][cq] = v.x; t[r][cq + 1] = v.y; t[r][cq + 2] = v.z; t[r][cq + 3] = v.w;
    }
    __syncthreads();
    #pragma unroll
    for (int it = 0; it < 2; it++) {
        int u = it * 256 + tid;
        int c = u >> 3, g = (u & 7) * 8;
        u16x8 o;
        #pragma unroll
        for (int v = 0; v < 8; v++) o[v] = f2bfu(t[g + v][c]);
        *(u16x8*)(oute + (size_t)(c0 + c) * R + r0 + g) = o;
    }
}

// ---------------- gating: scores, softmax, top-2, expert lists; also emits xb (x cast to bf16) ----------------
__global__ void gate_kernel(const float* __restrict__ x, const float* __restrict__ Wg,
                            const float* __restrict__ bg, int* __restrict__ counts,
                            int* __restrict__ tok_list, int* __restrict__ slot_list,
                            float* __restrict__ wslot, unsigned short* __restrict__ xb) {
    int wv = threadIdx.x >> 6, lane = threadIdx.x & 63;
    int n = blockIdx.x * 4 + wv;
    float acc[NE];
    #pragma unroll
    for (int e = 0; e < NE; e++) acc[e] = 0.f;
    const float* xr = x + (size_t)n * DIN;
    unsigned short* xbr = xb + (size_t)n * DIN;
    #pragma unroll
    for (int i = 0; i < DIN / 256; i++) {
        int d = i * 256 + lane * 4;
        float4 xv = *(const float4*)(xr + d);
        ushort4 o;
        o.x = f2bfu(xv.x); o.y = f2bfu(xv.y); o.z = f2bfu(xv.z); o.w = f2bfu(xv.w);
        *(ushort4*)(xbr + d) = o;
        const float* w = Wg + (size_t)d * NE;
        #pragma unroll
        for (int u = 0; u < 4; u++) {
            float xs = (&xv.x)[u];
            float4 w0 = *(const float4*)(w + u * NE);
            float4 w1 = *(const float4*)(w + u * NE + 4);
            acc[0] += xs * w0.x; acc[1] += xs * w0.y; acc[2] += xs * w0.z; acc[3] += xs * w0.w;
            acc[4] += xs * w1.x; acc[5] += xs * w1.y; acc[6] += xs * w1.z; acc[7] += xs * w1.w;
        }
    }
    #pragma unroll
    for (int off = 32; off; off >>= 1)
        #pragma unroll
        for (int e = 0; e < NE; e++) acc[e] += __shfl_down(acc[e], off);
    if (lane == 0) {
        float s[NE], p[NE];
        float mx = -1e30f;
        #pragma unroll
        for (int e = 0; e < NE; e++) { s[e] = acc[e] + bg[e]; mx = fmaxf(mx, s[e]); }
        float sum = 0.f;
        #pragma unroll
        for (int e = 0; e < NE; e++) { p[e] = expf(s[e] - mx); sum += p[e]; }
        float inv = 1.f / sum;
        int e0 = 0;
        #pragma unroll
        for (int e = 1; e < NE; e++) if (s[e] > s[e0]) e0 = e;
        int e1 = (e0 == 0) ? 1 : 0;
        #pragma unroll
        for (int e = 0; e < NE; e++) if (e != e0 && s[e] > s[e1]) e1 = e;
        float p0 = p[e0] * inv, p1 = p[e1] * inv;
        float rn = 1.f / (p0 + p1 + 1e-8f);
        int pos0 = atomicAdd(&counts[e0], 1);
        tok_list[e0 * N_TOK + pos0] = n; slot_list[e0 * N_TOK + pos0] = 2 * n;     wslot[e0 * N_TOK + pos0] = p0 * rn;
        int pos1 = atomicAdd(&counts[e1], 1);
        tok_list[e1 * N_TOK + pos1] = n; slot_list[e1 * N_TOK + pos1] = 2 * n + 1; wslot[e1 * N_TOK + pos1] = p1 * rn;
    }
}

// ---------------- grouped gather-GEMM, 128x128 tile, BK=64, bf16 MFMA ----------------
// 1D grid, XCD-swizzled decode: expert = blockIdx&7 so (with round-robin block->XCD
// mapping) each expert's whole GEMM runs on one XCD; tile_n fastest within the XCD so
// blocks sharing an A-tile are co-resident on the same L2. LDS staging XOR-swizzled
// (k8 ^ row) -> zero bank conflicts (verified R2).
template <int KDIM, int NDIM, bool IS_GEMM1>
__global__ __launch_bounds__(256, 4)
void moe_gemm(const unsigned short* __restrict__ Asrc, const unsigned short* __restrict__ Bt,
              const float* __restrict__ bias, unsigned short* __restrict__ Hdst,
              float* __restrict__ Odst, const int* __restrict__ counts,
              const int* __restrict__ tok_list, const int* __restrict__ slot_list,
              const float* __restrict__ wslot) {
    constexpr int NT_N = NDIM / 128;
    int ell = blockIdx.x;
    int e = ell & 7;
    int s = ell >> 3;
    int tile_n = s % NT_N;
    int tile_m = s / NT_N;
    int count = counts[e];
    if (tile_m * 128 >= count) return;

    __shared__ __align__(16) unsigned short As[128 * 64];
    __shared__ __align__(16) unsigned short Bs[128 * 64];
    __shared__ int rowid_s[128];
    __shared__ int outid_s[128];
    __shared__ float w_s[128];

    int tid = threadIdx.x;
    if (tid < 128) {
        int r = tile_m * 128 + tid;
        int rr = (r < count) ? r : tile_m * 128;
        int base = e * N_TOK + rr;
        if (IS_GEMM1) { rowid_s[tid] = tok_list[base]; outid_s[tid] = slot_list[base]; }
        else          { rowid_s[tid] = slot_list[base]; outid_s[tid] = tok_list[base]; w_s[tid] = wslot[base]; }
    }
    __syncthreads();

    int lane = tid & 63;
    int wv = tid >> 6;

    int ric = lane >> 3;
    int k8  = (lane & 7) ^ ric;
    const unsigned short* aptr[4];
    const unsigned short* bptr[4];
    #pragma unroll
    for (int i = 0; i < 4; i++) {
        int c = wv * 4 + i;
        int row = c * 8 + ric;
        aptr[i] = Asrc + (size_t)rowid_s[row] * KDIM + k8 * 8;
        bptr[i] = Bt + ((size_t)e * NDIM + tile_n * 128 + row) * KDIM + k8 * 8;
    }

    f32x4 acc[4][4];
    #pragma unroll
    for (int i = 0; i < 4; i++)
        #pragma unroll
        for (int j = 0; j < 4; j++) acc[i][j] = (f32x4){0.f, 0.f, 0.f, 0.f};

    int wm = (wv >> 1) * 64, wn = (wv & 1) * 64;
    int r16 = lane & 15, quad = lane >> 4;

    for (int kk = 0; kk < KDIM / 64; kk++) {
        #pragma unroll
        for (int i = 0; i < 4; i++) {
            gload_lds16(aptr[i] + kk * 64, (void*)(As + (wv * 4 + i) * 512));
            gload_lds16(bptr[i] + kk * 64, (void*)(Bs + (wv * 4 + i) * 512));
        }
        __syncthreads();
        #pragma unroll
        for (int kh = 0; kh < 2; kh++) {
            int swk = ((kh * 4 + quad) ^ (r16 & 7)) * 8;   // un-swizzle at read time
            bf16x8 av[4], bv[4];
            #pragma unroll
            for (int i = 0; i < 4; i++)
                av[i] = *(const bf16x8*)(As + (wm + i * 16 + r16) * 64 + swk);
            #pragma unroll
            for (int j = 0; j < 4; j++)
                bv[j] = *(const bf16x8*)(Bs + (wn + j * 16 + r16) * 64 + swk);
            #pragma unroll
            for (int i = 0; i < 4; i++)
                #pragma unroll
                for (int j = 0; j < 4; j++)
                    acc[i][j] = __builtin_amdgcn_mfma_f32_16x16x32_bf16(av[i], bv[j], acc[i][j], 0, 0, 0);
        }
        __syncthreads();
    }

    // epilogue: D row = quad*4+reg, col = lane&15 within each 16x16 tile
    float bias_r[4];
    #pragma unroll
    for (int j = 0; j < 4; j++)
        bias_r[j] = bias[(size_t)e * NDIM + tile_n * 128 + wn + j * 16 + r16];
    #pragma unroll
    for (int i = 0; i < 4; i++) {
        #pragma unroll
        for (int reg = 0; reg < 4; reg++) {
            int r = wm + i * 16 + quad * 4 + reg;
            if (tile_m * 128 + r >= count) continue;
            #pragma unroll
            for (int j = 0; j < 4; j++) {
                int col = tile_n * 128 + wn + j * 16 + r16;
                float v = acc[i][j][reg] + bias_r[j];
                if (IS_GEMM1) {
                    v = fmaxf(v, 0.f);
                    Hdst[(size_t)outid_s[r] * NDIM + col] = f2bfu(v);
                } else {
                    atomicAdd(&Odst[(size_t)outid_s[r] * NDIM + col], w_s[r] * v);
                }
            }
        }
    }
}

extern "C" void kernel_launch(void* const* d_in, const int* in_sizes, int n_in,
                              void* d_out, int out_size, void* d_ws, size_t ws_size,
                              hipStream_t stream) {
    const float* x  = (const float*)d_in[0];
    const float* W1 = (const float*)d_in[1];
    const float* b1 = (const float*)d_in[2];
    const float* W2 = (const float*)d_in[3];
    const float* b2 = (const float*)d_in[4];
    const float* Wg = (const float*)d_in[5];
    const float* bg = (const float*)d_in[6];
    float* out = (float*)d_out;

    char* ws = (char*)d_ws;
    unsigned short* xb  = (unsigned short*)(ws + 0);            // 16 MB
    unsigned short* w1t = (unsigned short*)(ws + 16777216);     // 64 MB  [E][DHID][DIN]
    unsigned short* w2t = (unsigned short*)(ws + 83886080);     // 64 MB  [E][DOUT][DHID]
    unsigned short* h   = (unsigned short*)(ws + 150994944);    // 128 MB [2N][DHID]
    int*   counts    = (int*)(ws + 285212672);
    int*   tok_list  = (int*)(ws + 285212928);
    int*   slot_list = (int*)(ws + 285475072);
    float* wslot     = (float*)(ws + 285737216);

    hipMemsetAsync(counts, 0, 256, stream);
    hipMemsetAsync(d_out, 0, (size_t)out_size * sizeof(float), stream);

    transpose_cast_kernel<<<dim3(DHID / 64, DIN / 64, NE), 256, 0, stream>>>(W1, w1t, DIN, DHID);
    transpose_cast_kernel<<<dim3(DOUT / 64, DHID / 64, NE), 256, 0, stream>>>(W2, w2t, DHID, DOUT);
    gate_kernel<<<N_TOK / 4, 256, 0, stream>>>(x, Wg, bg, counts, tok_list, slot_list, wslot, xb);

    moe_gemm<DIN, DHID, true><<<NE * (N_TOK / 128) * (DHID / 128), 256, 0, stream>>>(
        xb, w1t, b1, h, nullptr, counts, tok_list, slot_list, wslot);
    moe_gemm<DHID, DOUT, false><<<NE * (N_TOK / 128) * (DOUT / 128), 256, 0, stream>>>(
        h, w2t, b2, nullptr, out, counts, tok_list, slot_list, wslot);
}

// Round 4
// 889.585 us; speedup vs baseline: 1.1470x; 1.0074x over previous
//
#include <hip/hip_runtime.h>
#include <hip/hip_bf16.h>
#include <stdint.h>

#define N_TOK 8192
#define DIN   1024
#define DHID  4096
#define DOUT  1024
#define NE    8

typedef __attribute__((ext_vector_type(8))) __bf16 bf16x8;
typedef __attribute__((ext_vector_type(4))) float  f32x4;
typedef __attribute__((ext_vector_type(8))) unsigned short u16x8;

// RNE float->bf16 (finite inputs)
__device__ __forceinline__ unsigned short f2bfu(float f) {
    union { float f; unsigned u; } a; a.f = f;
    unsigned r = a.u + 0x7FFF + ((a.u >> 16) & 1);
    return (unsigned short)(r >> 16);
}

__device__ __forceinline__ void gload_lds16(const void* g, void* l) {
    __builtin_amdgcn_global_load_lds(
        (__attribute__((address_space(1))) void*)(void*)g,
        (__attribute__((address_space(3))) void*)l,
        16, 0, 0);
}

// ------------- cast + transpose weights: in [R][C] f32 -> out [C][R] bf16, per expert -------------
__global__ void transpose_cast_kernel(const float* __restrict__ in, unsigned short* __restrict__ out,
                                      int R, int C) {
    __shared__ float t[64][65];
    const size_t RC = (size_t)R * C;
    const float* ine = in + (size_t)blockIdx.z * RC;
    unsigned short* oute = out + (size_t)blockIdx.z * RC;
    int c0 = blockIdx.x * 64, r0 = blockIdx.y * 64;
    int tid = threadIdx.x;
    #pragma unroll
    for (int it = 0; it < 4; it++) {
        int idx = it * 256 + tid;
        int r = idx >> 4, cq = (idx & 15) * 4;
        float4 v = *(const float4*)(ine + (size_t)(r0 + r) * C + c0 + cq);
        t[r][cq] = v.x; t[r][cq + 1] = v.y; t[r][cq + 2] = v.z; t[r][cq + 3] = v.w;
    }
    __syncthreads();
    #pragma unroll
    for (int it = 0; it < 2; it++) {
        int u = it * 256 + tid;
        int c = u >> 3, g = (u & 7) * 8;
        u16x8 o;
        #pragma unroll
        for (int v = 0; v < 8; v++) o[v] = f2bfu(t[g + v][c]);
        *(u16x8*)(oute + (size_t)(c0 + c) * R + r0 + g) = o;
    }
}

// ---------------- gating: scores, softmax, top-2, expert lists; also emits xb (x cast to bf16) ----------------
__global__ void gate_kernel(const float* __restrict__ x, const float* __restrict__ Wg,
                            const float* __restrict__ bg, int* __restrict__ counts,
                            int* __restrict__ tok_list, int* __restrict__ slot_list,
                            float* __restrict__ wslot, unsigned short* __restrict__ xb) {
    int wv = threadIdx.x >> 6, lane = threadIdx.x & 63;
    int n = blockIdx.x * 4 + wv;
    float acc[NE];
    #pragma unroll
    for (int e = 0; e < NE; e++) acc[e] = 0.f;
    const float* xr = x + (size_t)n * DIN;
    unsigned short* xbr = xb + (size_t)n * DIN;
    #pragma unroll
    for (int i = 0; i < DIN / 256; i++) {
        int d = i * 256 + lane * 4;
        float4 xv = *(const float4*)(xr + d);
        ushort4 o;
        o.x = f2bfu(xv.x); o.y = f2bfu(xv.y); o.z = f2bfu(xv.z); o.w = f2bfu(xv.w);
        *(ushort4*)(xbr + d) = o;
        const float* w = Wg + (size_t)d * NE;
        #pragma unroll
        for (int u = 0; u < 4; u++) {
            float xs = (&xv.x)[u];
            float4 w0 = *(const float4*)(w + u * NE);
            float4 w1 = *(const float4*)(w + u * NE + 4);
            acc[0] += xs * w0.x; acc[1] += xs * w0.y; acc[2] += xs * w0.z; acc[3] += xs * w0.w;
            acc[4] += xs * w1.x; acc[5] += xs * w1.y; acc[6] += xs * w1.z; acc[7] += xs * w1.w;
        }
    }
    #pragma unroll
    for (int off = 32; off; off >>= 1)
        #pragma unroll
        for (int e = 0; e < NE; e++) acc[e] += __shfl_down(acc[e], off);
    if (lane == 0) {
        float s[NE], p[NE];
        float mx = -1e30f;
        #pragma unroll
        for (int e = 0; e < NE; e++) { s[e] = acc[e] + bg[e]; mx = fmaxf(mx, s[e]); }
        float sum = 0.f;
        #pragma unroll
        for (int e = 0; e < NE; e++) { p[e] = expf(s[e] - mx); sum += p[e]; }
        float inv = 1.f / sum;
        int e0 = 0;
        #pragma unroll
        for (int e = 1; e < NE; e++) if (s[e] > s[e0]) e0 = e;
        int e1 = (e0 == 0) ? 1 : 0;
        #pragma unroll
        for (int e = 0; e < NE; e++) if (e != e0 && s[e] > s[e1]) e1 = e;
        float p0 = p[e0] * inv, p1 = p[e1] * inv;
        float rn = 1.f / (p0 + p1 + 1e-8f);
        int pos0 = atomicAdd(&counts[e0], 1);
        tok_list[e0 * N_TOK + pos0] = n; slot_list[e0 * N_TOK + pos0] = 2 * n;     wslot[e0 * N_TOK + pos0] = p0 * rn;
        int pos1 = atomicAdd(&counts[e1], 1);
        tok_list[e1 * N_TOK + pos1] = n; slot_list[e1 * N_TOK + pos1] = 2 * n + 1; wslot[e1 * N_TOK + pos1] = p1 * rn;
    }
}

// ---------------- persistent grouped gather-GEMM, 128x128 tile, BK=64, bf16 MFMA ----------------
// Grid = 1024 = 8 experts x 128 persistent blocks. Block's expert e = blockIdx&7 is fixed
// (stride 1024 === 0 mod 8), so with round-robin block->XCD mapping each expert stays on one
// XCD -> its B panel lives in that L2 (R3: FETCH 633->140 MB). Items decoded tile_n-fastest,
// tile_m-last => monotone tile_m, dead tail handled by break (no dispatch churn).
// SPLITK: K split into SPLITK ranges merged by the f32 atomicAdd epilogue (bias added in
// range 0 only). LDS staging XOR-swizzled (k8 ^ row) -> 0 bank conflicts (verified R2).
template <int KDIM, int NDIM, bool IS_GEMM1, int SPLITK>
__global__ __launch_bounds__(256, 4)
void moe_gemm(const unsigned short* __restrict__ Asrc, const unsigned short* __restrict__ Bt,
              const float* __restrict__ bias, unsigned short* __restrict__ Hdst,
              float* __restrict__ Odst, const int* __restrict__ counts,
              const int* __restrict__ tok_list, const int* __restrict__ slot_list,
              const float* __restrict__ wslot) {
    constexpr int NT_N = NDIM / 128;
    constexpr int NT_M = N_TOK / 128;
    constexpr int KLEN = KDIM / SPLITK;

    int e = blockIdx.x & 7;
    int local = blockIdx.x >> 3;          // 0..127
    int count = counts[e];

    __shared__ __align__(16) unsigned short As[128 * 64];
    __shared__ __align__(16) unsigned short Bs[128 * 64];
    __shared__ int rowid_s[128];
    __shared__ int outid_s[128];
    __shared__ float w_s[128];

    int tid = threadIdx.x;
    int lane = tid & 63;
    int wv = tid >> 6;
    int ric = lane >> 3;
    int k8  = (lane & 7) ^ ric;
    int wm = (wv >> 1) * 64, wn = (wv & 1) * 64;
    int r16 = lane & 15, quad = lane >> 4;

    for (int w = local; ; w += 128) {
        int tile_n = w % NT_N;
        int r = w / NT_N;
        int kh = r % SPLITK;
        int tile_m = r / SPLITK;
        if (tile_m >= NT_M) break;
        if (tile_m * 128 >= count) break;   // tile_m monotone => nothing left

        __syncthreads();   // prior item's epilogue reads of outid_s/w_s must finish
        if (tid < 128) {
            int rr = tile_m * 128 + tid;
            if (rr >= count) rr = tile_m * 128;
            int base = e * N_TOK + rr;
            if (IS_GEMM1) { rowid_s[tid] = tok_list[base]; outid_s[tid] = slot_list[base]; }
            else          { rowid_s[tid] = slot_list[base]; outid_s[tid] = tok_list[base]; w_s[tid] = wslot[base]; }
        }
        __syncthreads();

        const int k0 = kh * KLEN;
        const unsigned short* aptr[4];
        const unsigned short* bptr[4];
        #pragma unroll
        for (int i = 0; i < 4; i++) {
            int c = wv * 4 + i;
            int row = c * 8 + ric;
            aptr[i] = Asrc + (size_t)rowid_s[row] * KDIM + k0 + k8 * 8;
            bptr[i] = Bt + ((size_t)e * NDIM + tile_n * 128 + row) * KDIM + k0 + k8 * 8;
        }

        f32x4 acc[4][4];
        #pragma unroll
        for (int i = 0; i < 4; i++)
            #pragma unroll
            for (int j = 0; j < 4; j++) acc[i][j] = (f32x4){0.f, 0.f, 0.f, 0.f};

        for (int kk = 0; kk < KLEN / 64; kk++) {
            #pragma unroll
            for (int i = 0; i < 4; i++) {
                gload_lds16(aptr[i] + kk * 64, (void*)(As + (wv * 4 + i) * 512));
                gload_lds16(bptr[i] + kk * 64, (void*)(Bs + (wv * 4 + i) * 512));
            }
            __syncthreads();
            #pragma unroll
            for (int kh2 = 0; kh2 < 2; kh2++) {
                int swk = ((kh2 * 4 + quad) ^ (r16 & 7)) * 8;   // un-swizzle at read time
                bf16x8 av[4], bv[4];
                #pragma unroll
                for (int i = 0; i < 4; i++)
                    av[i] = *(const bf16x8*)(As + (wm + i * 16 + r16) * 64 + swk);
                #pragma unroll
                for (int j = 0; j < 4; j++)
                    bv[j] = *(const bf16x8*)(Bs + (wn + j * 16 + r16) * 64 + swk);
                #pragma unroll
                for (int i = 0; i < 4; i++)
                    #pragma unroll
                    for (int j = 0; j < 4; j++)
                        acc[i][j] = __builtin_amdgcn_mfma_f32_16x16x32_bf16(av[i], bv[j], acc[i][j], 0, 0, 0);
            }
            __syncthreads();
        }

        // epilogue: D row = quad*4+reg, col = lane&15 within each 16x16 tile
        float bias_r[4];
        #pragma unroll
        for (int j = 0; j < 4; j++)
            bias_r[j] = bias[(size_t)e * NDIM + tile_n * 128 + wn + j * 16 + r16];
        #pragma unroll
        for (int i = 0; i < 4; i++) {
            #pragma unroll
            for (int reg = 0; reg < 4; reg++) {
                int rr = wm + i * 16 + quad * 4 + reg;
                if (tile_m * 128 + rr >= count) continue;
                #pragma unroll
                for (int j = 0; j < 4; j++) {
                    int col = tile_n * 128 + wn + j * 16 + r16;
                    float v = acc[i][j][reg];
                    if (IS_GEMM1) {
                        v = fmaxf(v + bias_r[j], 0.f);
                        Hdst[(size_t)outid_s[rr] * NDIM + col] = f2bfu(v);
                    } else {
                        if (kh == 0) v += bias_r[j];
                        atomicAdd(&Odst[(size_t)outid_s[rr] * NDIM + col], w_s[rr] * v);
                    }
                }
            }
        }
    }
}

extern "C" void kernel_launch(void* const* d_in, const int* in_sizes, int n_in,
                              void* d_out, int out_size, void* d_ws, size_t ws_size,
                              hipStream_t stream) {
    const float* x  = (const float*)d_in[0];
    const float* W1 = (const float*)d_in[1];
    const float* b1 = (const float*)d_in[2];
    const float* W2 = (const float*)d_in[3];
    const float* b2 = (const float*)d_in[4];
    const float* Wg = (const float*)d_in[5];
    const float* bg = (const float*)d_in[6];
    float* out = (float*)d_out;

    char* ws = (char*)d_ws;
    unsigned short* xb  = (unsigned short*)(ws + 0);            // 16 MB
    unsigned short* w1t = (unsigned short*)(ws + 16777216);     // 64 MB  [E][DHID][DIN]
    unsigned short* w2t = (unsigned short*)(ws + 83886080);     // 64 MB  [E][DOUT][DHID]
    unsigned short* h   = (unsigned short*)(ws + 150994944);    // 128 MB [2N][DHID]
    int*   counts    = (int*)(ws + 285212672);
    int*   tok_list  = (int*)(ws + 285212928);
    int*   slot_list = (int*)(ws + 285475072);
    float* wslot     = (float*)(ws + 285737216);

    hipMemsetAsync(counts, 0, 256, stream);
    hipMemsetAsync(d_out, 0, (size_t)out_size * sizeof(float), stream);

    transpose_cast_kernel<<<dim3(DHID / 64, DIN / 64, NE), 256, 0, stream>>>(W1, w1t, DIN, DHID);
    transpose_cast_kernel<<<dim3(DOUT / 64, DHID / 64, NE), 256, 0, stream>>>(W2, w2t, DHID, DOUT);
    gate_kernel<<<N_TOK / 4, 256, 0, stream>>>(x, Wg, bg, counts, tok_list, slot_list, wslot, xb);

    moe_gemm<DIN, DHID, true, 1><<<1024, 256, 0, stream>>>(
        xb, w1t, b1, h, nullptr, counts, tok_list, slot_list, wslot);
    moe_gemm<DHID, DOUT, false, 2><<<1024, 256, 0, stream>>>(
        h, w2t, b2, nullptr, out, counts, tok_list, slot_list, wslot);
}